// Round 2
// baseline (822.325 us; speedup 1.0000x reference)
//
#include <hip/hip_runtime.h>
#include <cstdint>
#include <cstddef>

// Problem constants (B, N, C) = (4, 6144, 256), M = 3, n = 2048
#define B_   4
#define N_   6144
#define C_   256
#define M_   3
#define NLOC 2048

static_assert(N_ == M_ * NLOC, "shape");

typedef __bf16 bf16;
typedef __bf16 bf16x8 __attribute__((ext_vector_type(8)));  // MFMA A/B operand (4 VGPRs)
typedef float  f32x4  __attribute__((ext_vector_type(4)));  // MFMA C/D operand / 16B chunk

// ---------------------------------------------------------------------------
// Tiled transpose + fp32->bf16 convert: src (S, R, Cc) f32 -> dst (S, Cc, R) bf16
// ---------------------------------------------------------------------------
__global__ void transpose_k(const float* __restrict__ src, bf16* __restrict__ dst,
                            int R, int Cc) {
    __shared__ bf16 tile[32][33];
    const int s  = blockIdx.z;
    const int rb = blockIdx.y * 32, cb = blockIdx.x * 32;
    const float* sp = src + (size_t)s * R * Cc;
    bf16*        dp = dst + (size_t)s * R * Cc;
    const int tx = threadIdx.x, ty = threadIdx.y;  // 32 x 8
#pragma unroll
    for (int i = 0; i < 4; ++i)
        tile[ty + 8 * i][tx] = (bf16)sp[(size_t)(rb + ty + 8 * i) * Cc + (cb + tx)];
    __syncthreads();
#pragma unroll
    for (int i = 0; i < 4; ++i)
        dp[(size_t)(cb + ty + 8 * i) * R + (rb + tx)] = tile[tx][ty + 8 * i];
}

// ---------------------------------------------------------------------------
// Kernel D: per (b, modal, rowtile of 64) compute
//   aggr_pre[r, c] = (1/max(sum_j |e_masked[r,j]|, 1e-12)) * sum_j e_masked[r,j] * x[j, c]
// e is fp32 in global; converted to bf16 during A staging, diagonal zeroed,
// L1 row-sum accumulated from the same staged values (no separate pass).
// Tile: 64 rows x 256 cols, BK=32. 4 waves; wave w handles cols [w*64, w*64+64).
// ---------------------------------------------------------------------------
__global__ __launch_bounds__(256) void aggr_gemm_k(
    const float* __restrict__ e,   // (B, N, N) fp32
    const bf16* __restrict__ xT,   // (B, C, N) bf16 ws
    bf16* __restrict__ aggr)       // (B, N, C) bf16 ws
{
    __shared__ __align__(16) bf16 Abuf[64 * 32];   // [row][k]
    __shared__ __align__(16) bf16 Bbuf[256 * 32];  // [col][k]
    __shared__ float rsum[256];                    // 4 partials per row

    const int rt = blockIdx.x, i = blockIdx.y, b = blockIdx.z;
    const int t = threadIdx.x;
    const int w = t >> 6, lane = t & 63, l15 = lane & 15, quad = lane >> 4;

    const int r_stage = t >> 2;       // 0..63: staged row
    const int ch8 = (t & 3) * 8;      // k-chunk within BK (8 elements)

    const int diag_local = rt * 64 + r_stage;  // local diag col for this row
    const float* eptr = e + ((size_t)(b * N_ + i * NLOC + rt * 64 + r_stage)) * N_
                          + i * NLOC + ch8;
    const bf16* xTbase = xT + (size_t)(b * C_) * N_ + i * NLOC + ch8;

    f32x4 acc[4][4];
#pragma unroll
    for (int mt = 0; mt < 4; ++mt)
#pragma unroll
        for (int nt = 0; nt < 4; ++nt) { f32x4 z = {0.f, 0.f, 0.f, 0.f}; acc[mt][nt] = z; }

    float psum = 0.f;  // partial L1 row sum (this thread's k-chunks of its row)

    for (int kk = 0; kk < NLOC; kk += 32) {
        __syncthreads();
        // ---- stage A (e rows fp32 -> bf16), zero diagonal, accumulate |.| ----
        f32x4 v0 = *(const f32x4*)(const void*)(eptr + kk);
        f32x4 v1 = *(const f32x4*)(const void*)(eptr + kk + 4);
        float vals[8] = {v0[0], v0[1], v0[2], v0[3], v1[0], v1[1], v1[2], v1[3]};
        const int d = diag_local - kk - ch8;
        if ((unsigned)d < 8u) vals[d] = 0.f;
        bf16x8 ab;
#pragma unroll
        for (int j = 0; j < 8; ++j) {
            const bf16 h = (bf16)vals[j];
            ab[j] = h;
            psum += fabsf((float)h);
        }
        *(bf16x8*)(void*)&Abuf[r_stage * 32 + ch8] = ab;
        // ---- stage B (xT rows = output channels, already bf16) ----
#pragma unroll
        for (int q = 0; q < 4; ++q) {
            const int c = q * 64 + r_stage;
            f32x4 v = *(const f32x4*)(const void*)(xTbase + (size_t)c * N_ + kk);
            *(f32x4*)(void*)&Bbuf[c * 32 + ch8] = v;
        }
        __syncthreads();
        // ---- MFMA: 4 m-tiles x 4 n-tiles of 16x16x32 ----
        bf16x8 af[4];
#pragma unroll
        for (int mt = 0; mt < 4; ++mt)
            af[mt] = *(const bf16x8*)(const void*)&Abuf[(mt * 16 + l15) * 32 + quad * 8];
#pragma unroll
        for (int nt = 0; nt < 4; ++nt) {
            bf16x8 bv = *(const bf16x8*)(const void*)&Bbuf[(w * 64 + nt * 16 + l15) * 32 + quad * 8];
#pragma unroll
            for (int mt = 0; mt < 4; ++mt)
                acc[mt][nt] = __builtin_amdgcn_mfma_f32_16x16x32_bf16(af[mt], bv, acc[mt][nt], 0, 0, 0);
        }
    }

    // ---- reduce row sums: 4 partials per row laid out rsum[row*4 + chunk] ----
    rsum[t] = psum;  // t == r_stage*4 + (t&3)
    __syncthreads();

    // ---- epilogue: scale by 1/L1 and store bf16 ----
#pragma unroll
    for (int mt = 0; mt < 4; ++mt) {
#pragma unroll
        for (int reg = 0; reg < 4; ++reg) {
            const int rr = mt * 16 + quad * 4 + reg;  // local row 0..63
            const float s = rsum[rr * 4] + rsum[rr * 4 + 1] + rsum[rr * 4 + 2] + rsum[rr * 4 + 3];
            const float inv = 1.f / fmaxf(s, 1e-12f);
            bf16* op = aggr + ((size_t)(b * N_ + i * NLOC + rt * 64 + rr)) * C_;
#pragma unroll
            for (int nt = 0; nt < 4; ++nt) {
                const int c = w * 64 + nt * 16 + l15;
                op[c] = (bf16)(acc[mt][nt][reg] * inv);
            }
        }
    }
}

// ---------------------------------------------------------------------------
// Kernel E: per (b, modal, rowtile of 64):
//   feat = x @ W_feat[i] + b_feat[i];  ag = aggr_pre @ W_raw[i] + b_raw[i]
//   beta = sigmoid(feat.(w1+w3) + ag.(w2-w3) + b_beta[i])
//   h = ag + (feat-ag)*beta;  out = relu(LN(h)*gamma + lbeta)
// Wave owns 16 full rows (all 256 cols) -> per-row reductions are width-16
// shuffles, no cross-wave traffic.
// ---------------------------------------------------------------------------
__global__ __launch_bounds__(256) void node_final_k(
    const float* __restrict__ x,       // (B, N, C) fp32
    const bf16* __restrict__ aggr,     // (B, N, C) bf16 ws
    const bf16* __restrict__ WfT,      // (M, C, C) bf16 ws, [out][k]
    const bf16* __restrict__ WrT,      // (M, C, C) bf16 ws
    const float* __restrict__ b_feat,  // (M, C) fp32
    const float* __restrict__ b_raw,   // (M, C) fp32
    const float* __restrict__ W_beta,  // (M, 3C) fp32
    const float* __restrict__ b_beta,  // (M,) fp32
    const float* __restrict__ ln_g,    // (M, C) fp32
    const float* __restrict__ ln_b,    // (M, C) fp32
    float* __restrict__ out)           // (B, N, C) fp32
{
    __shared__ __align__(16) bf16 Ax[64 * 32], Ag[64 * 32];
    __shared__ __align__(16) bf16 Bf[256 * 32], Br[256 * 32];
    __shared__ float pbf[256], pbr[256], pwA[256], pwB[256], pgm[256], plb[256];

    const int rt = blockIdx.x, i = blockIdx.y, b = blockIdx.z;
    const int t = threadIdx.x;
    const int w = t >> 6, lane = t & 63, l15 = lane & 15, quad = lane >> 4;

    // per-channel params -> LDS as fp32 (one channel per thread)
    {
        const int c = t;
        const float w3 = W_beta[i * 768 + 512 + c];
        pbf[c] = b_feat[i * C_ + c];
        pbr[c] = b_raw[i * C_ + c];
        pwA[c] = W_beta[i * 768 + c] + w3;
        pwB[c] = W_beta[i * 768 + 256 + c] - w3;
        pgm[c] = ln_g[i * C_ + c];
        plb[c] = ln_b[i * C_ + c];
    }

    f32x4 accf[16], accg[16];
#pragma unroll
    for (int nt = 0; nt < 16; ++nt) { f32x4 z = {0.f, 0.f, 0.f, 0.f}; accf[nt] = z; accg[nt] = z; }

    const int r_stage = t >> 2;
    const int ch8 = (t & 3) * 8;
    const size_t nodeRow = (size_t)(b * N_ + i * NLOC + rt * 64 + r_stage);
    const float* xp = x   + nodeRow * C_ + ch8;
    const bf16* gp = aggr + nodeRow * C_ + ch8;
    const bf16* wf = WfT + (size_t)(i * C_) * C_ + ch8;
    const bf16* wr = WrT + (size_t)(i * C_) * C_ + ch8;

    for (int kk = 0; kk < C_; kk += 32) {
        __syncthreads();
        // x: fp32 -> bf16 during staging
        {
            f32x4 v0 = *(const f32x4*)(const void*)(xp + kk);
            f32x4 v1 = *(const f32x4*)(const void*)(xp + kk + 4);
            bf16x8 ax;
#pragma unroll
            for (int j = 0; j < 4; ++j) { ax[j] = (bf16)v0[j]; ax[j + 4] = (bf16)v1[j]; }
            *(bf16x8*)(void*)&Ax[r_stage * 32 + ch8] = ax;
        }
        *(f32x4*)(void*)&Ag[r_stage * 32 + ch8] = *(const f32x4*)(const void*)(gp + kk);
#pragma unroll
        for (int q = 0; q < 4; ++q) {
            const int o = q * 64 + r_stage;
            *(f32x4*)(void*)&Bf[o * 32 + ch8] = *(const f32x4*)(const void*)(wf + (size_t)o * C_ + kk);
            *(f32x4*)(void*)&Br[o * 32 + ch8] = *(const f32x4*)(const void*)(wr + (size_t)o * C_ + kk);
        }
        __syncthreads();
        const bf16x8 ax = *(const bf16x8*)(const void*)&Ax[(w * 16 + l15) * 32 + quad * 8];
        const bf16x8 ag = *(const bf16x8*)(const void*)&Ag[(w * 16 + l15) * 32 + quad * 8];
#pragma unroll
        for (int nt = 0; nt < 16; ++nt) {
            const bf16x8 bfv = *(const bf16x8*)(const void*)&Bf[(nt * 16 + l15) * 32 + quad * 8];
            const bf16x8 brv = *(const bf16x8*)(const void*)&Br[(nt * 16 + l15) * 32 + quad * 8];
            accf[nt] = __builtin_amdgcn_mfma_f32_16x16x32_bf16(ax, bfv, accf[nt], 0, 0, 0);
            accg[nt] = __builtin_amdgcn_mfma_f32_16x16x32_bf16(ag, brv, accg[nt], 0, 0, 0);
        }
    }

    const float bb = b_beta[i];
    const int rowbase = i * NLOC + rt * 64 + w * 16 + quad * 4;
#pragma unroll
    for (int reg = 0; reg < 4; ++reg) {
        // pass 1: beta logit
        float pb = 0.f;
#pragma unroll
        for (int nt = 0; nt < 16; ++nt) {
            const int c = nt * 16 + l15;
            const float f = accf[nt][reg] + pbf[c];
            const float g = accg[nt][reg] + pbr[c];
            pb += f * pwA[c] + g * pwB[c];
        }
#pragma unroll
        for (int off = 1; off < 16; off <<= 1) pb += __shfl_xor(pb, off, 16);
        const float beta = 1.f / (1.f + expf(-(pb + bb)));
        // pass 2: LN statistics
        float sh = 0.f, sh2 = 0.f;
#pragma unroll
        for (int nt = 0; nt < 16; ++nt) {
            const int c = nt * 16 + l15;
            const float f = accf[nt][reg] + pbf[c];
            const float g = accg[nt][reg] + pbr[c];
            const float h = g + (f - g) * beta;
            sh += h; sh2 += h * h;
        }
#pragma unroll
        for (int off = 1; off < 16; off <<= 1) {
            sh  += __shfl_xor(sh,  off, 16);
            sh2 += __shfl_xor(sh2, off, 16);
        }
        const float mu   = sh * (1.f / 256.f);
        const float var  = sh2 * (1.f / 256.f) - mu * mu;
        const float rstd = rsqrtf(var + 1e-5f);
        // pass 3: normalize + relu + store (fp32)
        float* op = out + (size_t)(b * N_ + rowbase + reg) * C_;
#pragma unroll
        for (int nt = 0; nt < 16; ++nt) {
            const int c = nt * 16 + l15;
            const float f = accf[nt][reg] + pbf[c];
            const float g = accg[nt][reg] + pbr[c];
            const float h = g + (f - g) * beta;
            const float o = (h - mu) * rstd * pgm[c] + plb[c];
            op[c] = fmaxf(o, 0.f);
        }
    }
}

// ---------------------------------------------------------------------------
extern "C" void kernel_launch(void* const* d_in, const int* in_sizes, int n_in,
                              void* d_out, int out_size, void* d_ws, size_t ws_size,
                              hipStream_t stream) {
    const float* e       = (const float*)d_in[0];
    const float* x       = (const float*)d_in[1];
    // d_in[2] modal_id (int32): redundant (block structure is static)
    const float* W_feat  = (const float*)d_in[3];
    const float* b_feat  = (const float*)d_in[4];
    const float* W_raw   = (const float*)d_in[5];
    const float* b_raw   = (const float*)d_in[6];
    const float* W_beta  = (const float*)d_in[7];
    const float* b_beta  = (const float*)d_in[8];
    const float* ln_g    = (const float*)d_in[9];
    const float* ln_b    = (const float*)d_in[10];
    float* out = (float*)d_out;

    // workspace layout (bytes), all bf16 intermediates
    char* ws = (char*)d_ws;
    bf16* xT   = (bf16*)(ws);                               // B*C*N  = 12,582,912 B
    bf16* WfT  = (bf16*)(ws + 12582912);                    //          393,216 B
    bf16* WrT  = (bf16*)(ws + 12582912 + 393216);           //          393,216 B
    bf16* aggr = (bf16*)(ws + 12582912 + 2 * 393216);       // B*N*C  = 12,582,912 B

    dim3 tb(32, 8);
    transpose_k<<<dim3(C_ / 32, N_ / 32, B_), tb, 0, stream>>>(x, xT, N_, C_);
    transpose_k<<<dim3(C_ / 32, C_ / 32, M_), tb, 0, stream>>>(W_feat, WfT, C_, C_);
    transpose_k<<<dim3(C_ / 32, C_ / 32, M_), tb, 0, stream>>>(W_raw, WrT, C_, C_);

    aggr_gemm_k<<<dim3(NLOC / 64, M_, B_), 256, 0, stream>>>(e, xT, aggr);
    node_final_k<<<dim3(NLOC / 64, M_, B_), 256, 0, stream>>>(
        x, aggr, WfT, WrT, b_feat, b_raw, W_beta, b_beta, ln_g, ln_b, out);
}